// Round 10
// baseline (273.367 us; speedup 1.0000x reference)
//
#include <hip/hip_runtime.h>
#include <hip/hip_bf16.h>

// GraphAttentionLayer fused kernels for MI355X (gfx950).
// N=8192, IN=512, OUT=64.
// r9 lesson: any kernel with the 256MB adj stream inside a latency-sensitive
// loop pays loaded-HBM latency per tile (compiler vmcnt FIFO drains). r10:
// split latency class from BW class.
//  K1 pack_wh (grid 2304): blocks 0..2047 stream adj -> 8MB bitmask via
//     __ballot (pure BW, 32 waves/CU, ~39us roofline); blocks 2048..2303 run
//     the r8 wh kernel (Wh bf16 transposed + rank-1 log2-scaled score vecs).
//  K2 attn (grid 256 x 512): block = 32 rows x 8192 cols, 8 waves. Bitmask
//     slice (32KB) LDS-resident; WhbT/W2L L2-resident; no max subtraction;
//     denominators via ones-MFMA; two row-groups share each bf fragment.

#define LOG2E 1.4426950408889634f

typedef __attribute__((ext_vector_type(8))) short  short8v;
typedef __attribute__((ext_vector_type(8))) unsigned short ushort8v;
typedef __attribute__((ext_vector_type(4))) float  f32x4;

__device__ __forceinline__ unsigned short f2bf(float f) {
    union { float f; unsigned int u; } x; x.f = f;
    unsigned int r = x.u + 0x7FFFu + ((x.u >> 16) & 1u);   // RNE
    return (unsigned short)(r >> 16);
}

// ---------------- Kernel 1: pack (adj -> bitmask) + wh ----------------
__global__ __launch_bounds__(256) void pack_wh_kernel(
        const float* __restrict__ h, const int* __restrict__ adj,
        const float* __restrict__ W, const float* __restrict__ a,
        unsigned int* __restrict__ bmask,
        unsigned short* __restrict__ WhbT,
        float* __restrict__ Wh1L, float* __restrict__ W2L) {
    const int wave = threadIdx.x >> 6;
    const int lane = threadIdx.x & 63;

    if (blockIdx.x < 2048) {
        // ---- pack role: wave -> one adj row; bit l of word-pair g = col g*64+l
        const int row = blockIdx.x * 4 + wave;
        const int* ap = adj + (size_t)row * 8192;
        unsigned long long* bp =
            reinterpret_cast<unsigned long long*>(bmask + (size_t)row * 256);
#pragma unroll 4
        for (int g = 0; g < 128; ++g) {
            int v = ap[g * 64 + lane];                 // coalesced 256B
            unsigned long long m = __ballot(v > 0);    // bit l = lane l
            if (lane == 0) bp[g] = m;
        }
        return;
    }

    // ---- wh role (r8 kernel, 256 blocks' worth) ----
    const int row0 = ((blockIdx.x - 2048) * 4 + wave) * 8;

    float acc[8];
#pragma unroll
    for (int rr = 0; rr < 8; ++rr) acc[rr] = 0.f;

    const float* hrow = h + (size_t)row0 * 512;
    for (int i = 0; i < 512; i += 4) {
        float w0 = W[(i + 0) * 64 + lane];
        float w1 = W[(i + 1) * 64 + lane];
        float w2 = W[(i + 2) * 64 + lane];
        float w3 = W[(i + 3) * 64 + lane];
#pragma unroll
        for (int rr = 0; rr < 8; ++rr) {
            float4 hv = *reinterpret_cast<const float4*>(hrow + (size_t)rr * 512 + i);
            acc[rr] = fmaf(hv.x, w0, fmaf(hv.y, w1, fmaf(hv.z, w2, fmaf(hv.w, w3, acc[rr]))));
        }
    }

    ushort8v bt;
#pragma unroll
    for (int rr = 0; rr < 8; ++rr) bt[rr] = f2bf(acc[rr]);
    *reinterpret_cast<ushort8v*>(WhbT + (size_t)lane * 8192 + row0) = bt;

    const float a1 = a[lane] * LOG2E, a2 = a[lane + 64] * LOG2E;
#pragma unroll
    for (int rr = 0; rr < 8; ++rr) {
        float t1 = acc[rr] * a1;
        float t2 = acc[rr] * a2;
#pragma unroll
        for (int off = 32; off; off >>= 1) {
            t1 += __shfl_xor(t1, off);
            t2 += __shfl_xor(t2, off);
        }
        if (lane == 0) { Wh1L[row0 + rr] = t1; W2L[row0 + rr] = t2; }
    }
}

// ---------------- Kernel 2: fused mask + softmax + PV ----------------
// grid 256 x 512 (8 waves). Block: 32 rows x 8192 cols. Per body (32 bodies):
// wave w covers cols [w*32 + it*256, +32); two 16-row groups share bf frags.
__global__ __launch_bounds__(512) void attn_kernel(
        const unsigned int* __restrict__ bmask,
        const unsigned short* __restrict__ WhbT,
        const float* __restrict__ Wh1L, const float* __restrict__ W2L,
        float* __restrict__ out) {
    __shared__ unsigned int bm_lds[32][260];   // 33.3KB, 16B-aligned rows
    __shared__ float sm_acc[8][64][17];        // 34.8KB, padded
    __shared__ float sm_l[8][2][16];           // 1KB

    const int tid  = threadIdx.x;
    const int w    = tid >> 6;
    const int lane = tid & 63;
    const int fr   = lane & 15;      // MFMA row (A) / col (B,D)
    const int cg   = lane >> 4;      // k-group
    const int i0   = blockIdx.x * 32;

    // ---- bitmask slice -> LDS (32 rows x 256 words) ----
#pragma unroll
    for (int k = 0; k < 4; ++k) {
        const int row = k * 8 + w;
        const int wc  = lane * 4;
        int4 v = *reinterpret_cast<const int4*>(bmask + (size_t)(i0 + row) * 256 + wc);
        *reinterpret_cast<int4*>(&bm_lds[row][wc]) = v;
    }
    __syncthreads();

    const float wh1a = Wh1L[i0 + fr];
    const float wh1b = Wh1L[i0 + 16 + fr];

    f32x4 acc[2][4];
#pragma unroll
    for (int rg = 0; rg < 2; ++rg)
#pragma unroll
        for (int f = 0; f < 4; ++f) acc[rg][f] = (f32x4){0.f, 0.f, 0.f, 0.f};
    f32x4 accl[2];
    accl[0] = (f32x4){0.f, 0.f, 0.f, 0.f};
    accl[1] = (f32x4){0.f, 0.f, 0.f, 0.f};

    short8v ones;
#pragma unroll
    for (int b = 0; b < 8; ++b) ones[b] = (short)0x3F80;   // bf16 1.0

    const float*          w2p = W2L + w * 32 + cg * 8;
    const unsigned short* bfp = WhbT + (size_t)fr * 8192 + w * 32 + cg * 8;
    const int sh = cg * 8;

    for (int it = 0; it < 32; ++it) {
        const int cbase = it * 256;
        float4 W0 = *reinterpret_cast<const float4*>(w2p + cbase);
        float4 W1 = *reinterpret_cast<const float4*>(w2p + cbase + 4);
        short8v bf[4];
#pragma unroll
        for (int f = 0; f < 4; ++f)
            bf[f] = *reinterpret_cast<const short8v*>(bfp + (size_t)f * 16 * 8192 + cbase);

        const int wi = it * 8 + w;
        const unsigned int wd0 = bm_lds[fr][wi];
        const unsigned int wd1 = bm_lds[16 + fr][wi];

#pragma unroll
        for (int rg = 0; rg < 2; ++rg) {
            const unsigned int wd  = rg ? wd1 : wd0;
            const float        wh1 = rg ? wh1b : wh1a;
            float p[8]; float t;
            t = wh1 + W0.x; t = fmaxf(t, 0.2f * t); p[0] = ((wd >> (sh + 0)) & 1u) ? __builtin_exp2f(t) : 0.f;
            t = wh1 + W0.y; t = fmaxf(t, 0.2f * t); p[1] = ((wd >> (sh + 1)) & 1u) ? __builtin_exp2f(t) : 0.f;
            t = wh1 + W0.z; t = fmaxf(t, 0.2f * t); p[2] = ((wd >> (sh + 2)) & 1u) ? __builtin_exp2f(t) : 0.f;
            t = wh1 + W0.w; t = fmaxf(t, 0.2f * t); p[3] = ((wd >> (sh + 3)) & 1u) ? __builtin_exp2f(t) : 0.f;
            t = wh1 + W1.x; t = fmaxf(t, 0.2f * t); p[4] = ((wd >> (sh + 4)) & 1u) ? __builtin_exp2f(t) : 0.f;
            t = wh1 + W1.y; t = fmaxf(t, 0.2f * t); p[5] = ((wd >> (sh + 5)) & 1u) ? __builtin_exp2f(t) : 0.f;
            t = wh1 + W1.z; t = fmaxf(t, 0.2f * t); p[6] = ((wd >> (sh + 6)) & 1u) ? __builtin_exp2f(t) : 0.f;
            t = wh1 + W1.w; t = fmaxf(t, 0.2f * t); p[7] = ((wd >> (sh + 7)) & 1u) ? __builtin_exp2f(t) : 0.f;

            union { short8v s8; __hip_bfloat162 h2[4]; } u;
            u.h2[0] = __float22bfloat162_rn(float2{p[0], p[1]});
            u.h2[1] = __float22bfloat162_rn(float2{p[2], p[3]});
            u.h2[2] = __float22bfloat162_rn(float2{p[4], p[5]});
            u.h2[3] = __float22bfloat162_rn(float2{p[6], p[7]});

#pragma unroll
            for (int f = 0; f < 4; ++f)
                acc[rg][f] = __builtin_amdgcn_mfma_f32_16x16x32_bf16(u.s8, bf[f], acc[rg][f], 0, 0, 0);
            accl[rg] = __builtin_amdgcn_mfma_f32_16x16x32_bf16(u.s8, ones, accl[rg], 0, 0, 0);
        }
    }

    // ---- epilogue: two passes (row-groups) over shared reduce buffers ----
#pragma unroll
    for (int rg = 0; rg < 2; ++rg) {
        __syncthreads();
#pragma unroll
        for (int f = 0; f < 4; ++f)
#pragma unroll
            for (int reg = 0; reg < 4; ++reg)
                sm_acc[w][lane][f * 4 + reg] = acc[rg][f][reg];
        if (fr == 0) {
#pragma unroll
            for (int reg = 0; reg < 4; ++reg) sm_l[w][rg][4 * cg + reg] = accl[rg][reg];
        }
        __syncthreads();

#pragma unroll
        for (int ss = 0; ss < 2; ++ss) {
            const int s = 2 * w + ss;
            const int f = s >> 2, reg = s & 3;
            float sum = 0.f;
#pragma unroll
            for (int ww = 0; ww < 8; ++ww) sum += sm_acc[ww][lane][s];
            const int R = 4 * cg + reg;
            float lrow = 0.f;
#pragma unroll
            for (int ww = 0; ww < 8; ++ww) lrow += sm_l[ww][rg][R];
            float y = sum / lrow;
            y = y > 0.f ? y : expm1f(y);          // ELU, alpha=1
            out[(size_t)(i0 + rg * 16 + R) * 64 + 16 * f + fr] = y;
        }
    }
}

extern "C" void kernel_launch(void* const* d_in, const int* in_sizes, int n_in,
                              void* d_out, int out_size, void* d_ws, size_t ws_size,
                              hipStream_t stream) {
    const float* h   = (const float*)d_in[0];
    const int*   adj = (const int*)d_in[1];
    const float* W   = (const float*)d_in[2];
    const float* a   = (const float*)d_in[3];

    unsigned short* WhbT  = (unsigned short*)d_ws;                   // 1 MB
    float*          Wh1L  = (float*)((char*)d_ws + (1 << 20));       // 32 KB
    float*          W2L   = Wh1L + 8192;                             // 32 KB
    unsigned int*   bmask = (unsigned int*)((char*)d_ws + (2 << 20)); // 8 MB

    pack_wh_kernel<<<2304, 256, 0, stream>>>(h, adj, W, a, bmask, WhbT, Wh1L, W2L);
    attn_kernel<<<256, 512, 0, stream>>>(bmask, WhbT, Wh1L, W2L, (float*)d_out);
}

// Round 11
// 120.776 us; speedup vs baseline: 2.2634x; 2.2634x over previous
//
#include <hip/hip_runtime.h>
#include <hip/hip_bf16.h>

// GraphAttentionLayer fused kernels for MI355X (gfx950).
// N=8192, IN=512, OUT=64.
// r10 lesson: scalar-dword adj streaming + __ballot = 510 GB/s (issue-bound).
// r11: pack via int4 loads (16B/lane) + VALU nibble pack + 3-level shfl_xor
// merge (no SALU/ballot on the load path). wh role first (blocks 0..255),
// pack role blocks 256..2303. attn kernel identical to r10.

#define LOG2E 1.4426950408889634f

typedef __attribute__((ext_vector_type(8))) short  short8v;
typedef __attribute__((ext_vector_type(8))) unsigned short ushort8v;
typedef __attribute__((ext_vector_type(4))) float  f32x4;

__device__ __forceinline__ unsigned short f2bf(float f) {
    union { float f; unsigned int u; } x; x.f = f;
    unsigned int r = x.u + 0x7FFFu + ((x.u >> 16) & 1u);   // RNE
    return (unsigned short)(r >> 16);
}

// ---------------- Kernel 1: wh (blocks 0..255) + pack (blocks 256..2303) ----
__global__ __launch_bounds__(256) void pack_wh_kernel(
        const float* __restrict__ h, const int* __restrict__ adj,
        const float* __restrict__ W, const float* __restrict__ a,
        unsigned int* __restrict__ bmask,
        unsigned short* __restrict__ WhbT,
        float* __restrict__ Wh1L, float* __restrict__ W2L) {
    const int wave = threadIdx.x >> 6;
    const int lane = threadIdx.x & 63;

    if (blockIdx.x >= 256) {
        // ---- pack role: wave -> one adj row; word w of row covers cols
        // [w*32, w*32+32), bit b = col w*32+b (same convention attn reads).
        const int row = (blockIdx.x - 256) * 4 + wave;
        const int4* ap4 = reinterpret_cast<const int4*>(adj + (size_t)row * 8192);
        unsigned int* bmp = bmask + (size_t)row * 256;
#pragma unroll 4
        for (int it = 0; it < 32; ++it) {
            int4 v = ap4[it * 64 + lane];          // 16B/lane, 1KB/wave
            unsigned int n = (unsigned int)(v.x > 0)
                           | ((unsigned int)(v.y > 0) << 1)
                           | ((unsigned int)(v.z > 0) << 2)
                           | ((unsigned int)(v.w > 0) << 3);
            n |= ((unsigned int)__shfl_xor((int)n, 1)) << 4;    // even lanes: 8 bits
            n |= ((unsigned int)__shfl_xor((int)n, 2)) << 8;    // lanes %4==0: 16 bits
            n |= ((unsigned int)__shfl_xor((int)n, 4)) << 16;   // lanes %8==0: 32 bits
            if ((lane & 7) == 0) bmp[it * 8 + (lane >> 3)] = n;
        }
        return;
    }

    // ---- wh role (r8 kernel, 256 blocks) ----
    const int row0 = (blockIdx.x * 4 + wave) * 8;

    float acc[8];
#pragma unroll
    for (int rr = 0; rr < 8; ++rr) acc[rr] = 0.f;

    const float* hrow = h + (size_t)row0 * 512;
    for (int i = 0; i < 512; i += 4) {
        float w0 = W[(i + 0) * 64 + lane];
        float w1 = W[(i + 1) * 64 + lane];
        float w2 = W[(i + 2) * 64 + lane];
        float w3 = W[(i + 3) * 64 + lane];
#pragma unroll
        for (int rr = 0; rr < 8; ++rr) {
            float4 hv = *reinterpret_cast<const float4*>(hrow + (size_t)rr * 512 + i);
            acc[rr] = fmaf(hv.x, w0, fmaf(hv.y, w1, fmaf(hv.z, w2, fmaf(hv.w, w3, acc[rr]))));
        }
    }

    ushort8v bt;
#pragma unroll
    for (int rr = 0; rr < 8; ++rr) bt[rr] = f2bf(acc[rr]);
    *reinterpret_cast<ushort8v*>(WhbT + (size_t)lane * 8192 + row0) = bt;

    const float a1 = a[lane] * LOG2E, a2 = a[lane + 64] * LOG2E;
#pragma unroll
    for (int rr = 0; rr < 8; ++rr) {
        float t1 = acc[rr] * a1;
        float t2 = acc[rr] * a2;
#pragma unroll
        for (int off = 32; off; off >>= 1) {
            t1 += __shfl_xor(t1, off);
            t2 += __shfl_xor(t2, off);
        }
        if (lane == 0) { Wh1L[row0 + rr] = t1; W2L[row0 + rr] = t2; }
    }
}

// ---------------- Kernel 2: fused mask + softmax + PV (r10, unchanged) ------
// grid 256 x 512 (8 waves). Block: 32 rows x 8192 cols.
__global__ __launch_bounds__(512) void attn_kernel(
        const unsigned int* __restrict__ bmask,
        const unsigned short* __restrict__ WhbT,
        const float* __restrict__ Wh1L, const float* __restrict__ W2L,
        float* __restrict__ out) {
    __shared__ unsigned int bm_lds[32][260];   // 33.3KB
    __shared__ float sm_acc[8][64][17];        // 34.8KB, padded
    __shared__ float sm_l[8][2][16];           // 1KB

    const int tid  = threadIdx.x;
    const int w    = tid >> 6;
    const int lane = tid & 63;
    const int fr   = lane & 15;      // MFMA row (A) / col (B,D)
    const int cg   = lane >> 4;      // k-group
    const int i0   = blockIdx.x * 32;

#pragma unroll
    for (int k = 0; k < 4; ++k) {
        const int row = k * 8 + w;
        const int wc  = lane * 4;
        int4 v = *reinterpret_cast<const int4*>(bmask + (size_t)(i0 + row) * 256 + wc);
        *reinterpret_cast<int4*>(&bm_lds[row][wc]) = v;
    }
    __syncthreads();

    const float wh1a = Wh1L[i0 + fr];
    const float wh1b = Wh1L[i0 + 16 + fr];

    f32x4 acc[2][4];
#pragma unroll
    for (int rg = 0; rg < 2; ++rg)
#pragma unroll
        for (int f = 0; f < 4; ++f) acc[rg][f] = (f32x4){0.f, 0.f, 0.f, 0.f};
    f32x4 accl[2];
    accl[0] = (f32x4){0.f, 0.f, 0.f, 0.f};
    accl[1] = (f32x4){0.f, 0.f, 0.f, 0.f};

    short8v ones;
#pragma unroll
    for (int b = 0; b < 8; ++b) ones[b] = (short)0x3F80;   // bf16 1.0

    const float*          w2p = W2L + w * 32 + cg * 8;
    const unsigned short* bfp = WhbT + (size_t)fr * 8192 + w * 32 + cg * 8;
    const int sh = cg * 8;

    for (int it = 0; it < 32; ++it) {
        const int cbase = it * 256;
        float4 W0 = *reinterpret_cast<const float4*>(w2p + cbase);
        float4 W1 = *reinterpret_cast<const float4*>(w2p + cbase + 4);
        short8v bf[4];
#pragma unroll
        for (int f = 0; f < 4; ++f)
            bf[f] = *reinterpret_cast<const short8v*>(bfp + (size_t)f * 16 * 8192 + cbase);

        const int wi = it * 8 + w;
        const unsigned int wd0 = bm_lds[fr][wi];
        const unsigned int wd1 = bm_lds[16 + fr][wi];

#pragma unroll
        for (int rg = 0; rg < 2; ++rg) {
            const unsigned int wd  = rg ? wd1 : wd0;
            const float        wh1 = rg ? wh1b : wh1a;
            float p[8]; float t;
            t = wh1 + W0.x; t = fmaxf(t, 0.2f * t); p[0] = ((wd >> (sh + 0)) & 1u) ? __builtin_exp2f(t) : 0.f;
            t = wh1 + W0.y; t = fmaxf(t, 0.2f * t); p[1] = ((wd >> (sh + 1)) & 1u) ? __builtin_exp2f(t) : 0.f;
            t = wh1 + W0.z; t = fmaxf(t, 0.2f * t); p[2] = ((wd >> (sh + 2)) & 1u) ? __builtin_exp2f(t) : 0.f;
            t = wh1 + W0.w; t = fmaxf(t, 0.2f * t); p[3] = ((wd >> (sh + 3)) & 1u) ? __builtin_exp2f(t) : 0.f;
            t = wh1 + W1.x; t = fmaxf(t, 0.2f * t); p[4] = ((wd >> (sh + 4)) & 1u) ? __builtin_exp2f(t) : 0.f;
            t = wh1 + W1.y; t = fmaxf(t, 0.2f * t); p[5] = ((wd >> (sh + 5)) & 1u) ? __builtin_exp2f(t) : 0.f;
            t = wh1 + W1.z; t = fmaxf(t, 0.2f * t); p[6] = ((wd >> (sh + 6)) & 1u) ? __builtin_exp2f(t) : 0.f;
            t = wh1 + W1.w; t = fmaxf(t, 0.2f * t); p[7] = ((wd >> (sh + 7)) & 1u) ? __builtin_exp2f(t) : 0.f;

            union { short8v s8; __hip_bfloat162 h2[4]; } u;
            u.h2[0] = __float22bfloat162_rn(float2{p[0], p[1]});
            u.h2[1] = __float22bfloat162_rn(float2{p[2], p[3]});
            u.h2[2] = __float22bfloat162_rn(float2{p[4], p[5]});
            u.h2[3] = __float22bfloat162_rn(float2{p[6], p[7]});

#pragma unroll
            for (int f = 0; f < 4; ++f)
                acc[rg][f] = __builtin_amdgcn_mfma_f32_16x16x32_bf16(u.s8, bf[f], acc[rg][f], 0, 0, 0);
            accl[rg] = __builtin_amdgcn_mfma_f32_16x16x32_bf16(u.s8, ones, accl[rg], 0, 0, 0);
        }
    }

#pragma unroll
    for (int rg = 0; rg < 2; ++rg) {
        __syncthreads();
#pragma unroll
        for (int f = 0; f < 4; ++f)
#pragma unroll
            for (int reg = 0; reg < 4; ++reg)
                sm_acc[w][lane][f * 4 + reg] = acc[rg][f][reg];
        if (fr == 0) {
#pragma unroll
            for (int reg = 0; reg < 4; ++reg) sm_l[w][rg][4 * cg + reg] = accl[rg][reg];
        }
        __syncthreads();

#pragma unroll
        for (int ss = 0; ss < 2; ++ss) {
            const int s = 2 * w + ss;
            const int f = s >> 2, reg = s & 3;
            float sum = 0.f;
#pragma unroll
            for (int ww = 0; ww < 8; ++ww) sum += sm_acc[ww][lane][s];
            const int R = 4 * cg + reg;
            float lrow = 0.f;
#pragma unroll
            for (int ww = 0; ww < 8; ++ww) lrow += sm_l[ww][rg][R];
            float y = sum / lrow;
            y = y > 0.f ? y : expm1f(y);          // ELU, alpha=1
            out[(size_t)(i0 + rg * 16 + R) * 64 + 16 * f + fr] = y;
        }
    }
}

extern "C" void kernel_launch(void* const* d_in, const int* in_sizes, int n_in,
                              void* d_out, int out_size, void* d_ws, size_t ws_size,
                              hipStream_t stream) {
    const float* h   = (const float*)d_in[0];
    const int*   adj = (const int*)d_in[1];
    const float* W   = (const float*)d_in[2];
    const float* a   = (const float*)d_in[3];

    unsigned short* WhbT  = (unsigned short*)d_ws;                   // 1 MB
    float*          Wh1L  = (float*)((char*)d_ws + (1 << 20));       // 32 KB
    float*          W2L   = Wh1L + 8192;                             // 32 KB
    unsigned int*   bmask = (unsigned int*)((char*)d_ws + (2 << 20)); // 8 MB

    pack_wh_kernel<<<2304, 256, 0, stream>>>(h, adj, W, a, bmask, WhbT, Wh1L, W2L);
    attn_kernel<<<256, 512, 0, stream>>>(bmask, WhbT, Wh1L, W2L, (float*)d_out);
}